// Round 1
// baseline (613.515 us; speedup 1.0000x reference)
//
#include <hip/hip_runtime.h>

// YOLO_GNN on MI355X — round 1: correct f32 implementation.
// Pipeline: conv1 -> conv2+GAP(fused) -> fcf -> fcc+top2 -> graph(An,cm) ->
//           agg -> h1p (expert layer1 + mean-fold) -> g (expert layer2) ->
//           M (comb@fin_w) -> out (final GCN rows<5 mix + mean over k).

typedef float f32x4 __attribute__((ext_vector_type(4)));

#define B 64
#define FEAT 1024
#define HID 512
#define OUTD 256
#define NC 80

// ---------------- zero ----------------
__global__ void k_zero(float* __restrict__ p, int n) {
    int i = blockIdx.x * 256 + threadIdx.x;
    if (i < n) p[i] = 0.f;
}

// ---------------- weight transpose: [co][k] -> [k][co] ----------------
__global__ void k_prep(const float* __restrict__ w1, const float* __restrict__ w2,
                       float* __restrict__ wt1, float* __restrict__ wt2) {
    int i = blockIdx.x * 256 + threadIdx.x;
    if (i < 864) {            // conv1: 32 co x 27 k
        int k = i >> 5, co = i & 31;
        wt1[i] = w1[co * 27 + k];
    }
    if (i < 18432) {          // conv2: 64 co x 288 k
        int k = i >> 6, co = i & 63;
        wt2[i] = w2[co * 288 + k];
    }
}

// ---------------- conv1: 3->32, stride 2, SAME (pad hi only), ReLU ----------------
__global__ __launch_bounds__(256) void k_conv1(const float* __restrict__ x,
                                               const float* __restrict__ wt1,
                                               const float* __restrict__ bias,
                                               float* __restrict__ out) {
    int gid = blockIdx.x * 256 + threadIdx.x;       // 64*112*112 = 802816 exactly
    int ox = gid % 112;
    int t = gid / 112;
    int oy = t % 112;
    int b = t / 112;
    float acc[32];
#pragma unroll
    for (int i = 0; i < 32; i++) acc[i] = 0.f;
    const float* xb = x + (size_t)b * 3 * 224 * 224;
#pragma unroll
    for (int ky = 0; ky < 3; ky++) {
        int iy = 2 * oy + ky;
#pragma unroll
        for (int kx = 0; kx < 3; kx++) {
            int ix = 2 * ox + kx;
            bool ok = (iy < 224) && (ix < 224);     // pad_lo=0, pad_hi=1
#pragma unroll
            for (int ci = 0; ci < 3; ci++) {
                float v = ok ? xb[((size_t)ci * 224 + iy) * 224 + ix] : 0.f;
                const float* w = wt1 + ((ci * 3 + ky) * 3 + kx) * 32;  // uniform -> s_load
#pragma unroll
                for (int co = 0; co < 32; co++) acc[co] = fmaf(v, w[co], acc[co]);
            }
        }
    }
    float* ob = out + (size_t)b * 32 * 12544 + oy * 112 + ox;
#pragma unroll
    for (int co = 0; co < 32; co++) {
        float r = acc[co] + bias[co];
        ob[(size_t)co * 12544] = r > 0.f ? r : 0.f;
    }
}

// ---------------- conv2 (32->64, s2, SAME) + ReLU + global-avg-pool, fused ----------------
__global__ __launch_bounds__(256) void k_conv2gap(const float* __restrict__ h1,
                                                  const float* __restrict__ wt2,
                                                  const float* __restrict__ bias,
                                                  float* __restrict__ pooled) {
    int b = blockIdx.y;
    int px = blockIdx.x * 256 + threadIdx.x;        // 13*256=3328 >= 3136
    bool pvalid = px < 3136;
    int ox = px % 56, oy = px / 56;
    float acc[64];
#pragma unroll
    for (int i = 0; i < 64; i++) acc[i] = 0.f;
    const float* hb = h1 + (size_t)b * 32 * 12544;
#pragma unroll
    for (int ky = 0; ky < 3; ky++) {
        int iy = 2 * oy + ky;
#pragma unroll
        for (int kx = 0; kx < 3; kx++) {
            int ix = 2 * ox + kx;
            bool ok = pvalid && (iy < 112) && (ix < 112);
#pragma unroll 2
            for (int ci = 0; ci < 32; ci++) {
                float v = ok ? hb[((size_t)ci * 112 + iy) * 112 + ix] : 0.f;
                const float* w = wt2 + ((ci * 9) + ky * 3 + kx) * 64;  // uniform -> s_load
#pragma unroll
                for (int co = 0; co < 64; co++) acc[co] = fmaf(v, w[co], acc[co]);
            }
        }
    }
    // bias + relu (only for valid pixels), then block-reduce per channel
    __shared__ float s_red[64 * 4];
    int lane = threadIdx.x & 63, wid = threadIdx.x >> 6;
#pragma unroll
    for (int co = 0; co < 64; co++) {
        float r = pvalid ? fmaxf(acc[co] + bias[co], 0.f) : 0.f;
#pragma unroll
        for (int s = 32; s > 0; s >>= 1) r += __shfl_xor(r, s);
        if (lane == 0) s_red[co * 4 + wid] = r;
    }
    __syncthreads();
    if (threadIdx.x < 64) {
        float v = s_red[threadIdx.x * 4] + s_red[threadIdx.x * 4 + 1] +
                  s_red[threadIdx.x * 4 + 2] + s_red[threadIdx.x * 4 + 3];
        atomicAdd(&pooled[b * 64 + threadIdx.x], v);
    }
}

// ---------------- feats = relu(pooled/3136 @ fcf_w + fcf_b) ----------------
__global__ __launch_bounds__(256) void k_fcf(const float* __restrict__ pooled,
                                             const float* __restrict__ w,
                                             const float* __restrict__ bias,
                                             float* __restrict__ feats) {
    int b = blockIdx.x;
    int f0 = threadIdx.x;
    float acc[4];
#pragma unroll
    for (int j = 0; j < 4; j++) acc[j] = bias[f0 + j * 256];
    for (int c = 0; c < 64; c++) {
        float pv = pooled[b * 64 + c] * (1.f / 3136.f);   // uniform
#pragma unroll
        for (int j = 0; j < 4; j++)
            acc[j] = fmaf(pv, w[c * 1024 + f0 + j * 256], acc[j]);
    }
#pragma unroll
    for (int j = 0; j < 4; j++)
        feats[b * 1024 + f0 + j * 256] = fmaxf(acc[j], 0.f);
}

// ---------------- logits + top2 (JAX top_k tie-break: lower index first) ----------------
__global__ __launch_bounds__(128) void k_fcc_top2(const float* __restrict__ feats,
                                                  const float* __restrict__ w,
                                                  const float* __restrict__ bias,
                                                  int* __restrict__ top_idx) {
    int b = blockIdx.x;
    int c = threadIdx.x;
    __shared__ float sl[80];
    if (c < 80) {
        float acc = bias[c];
        const f32x4* fv = (const f32x4*)(feats + (size_t)b * 1024);
        for (int f4 = 0; f4 < 256; f4++) {
            f32x4 fr = fv[f4];                            // uniform -> s_load
            int f = f4 * 4;
#pragma unroll
            for (int j = 0; j < 4; j++)
                acc = fmaf(fr[j], w[(f + j) * 80 + c], acc);
        }
        sl[c] = acc;
    }
    __syncthreads();
    if (threadIdx.x == 0) {
        int i1 = 0;
        float v1 = sl[0];
        for (int i = 1; i < 80; i++)
            if (sl[i] > v1) { v1 = sl[i]; i1 = i; }       // strict > keeps lowest index
        int i2 = -1;
        float v2 = 0.f;
        for (int i = 0; i < 80; i++) {
            if (i == i1) continue;
            if (i2 < 0 || sl[i] > v2) { v2 = sl[i]; i2 = i; }
        }
        top_idx[b * 2] = i1;
        top_idx[b * 2 + 1] = i2;
    }
}

// ---------------- per-sample 5-node graph: d2 via quarter norms/dots -> knn -> An, cm ---------
// Xg: node0 = feats; node i (1..4) = quarter i left-aligned at cols [0,256) (pad at END).
__global__ __launch_bounds__(256) void k_graph(const float* __restrict__ feats,
                                               float* __restrict__ An,
                                               float* __restrict__ cm,
                                               int* __restrict__ dropped) {
    int b = blockIdx.x;
    int t = threadIdx.x;  // exactly 256 = quarter length
    const float* fb = feats + (size_t)b * 1024;
    float q1 = fb[t], q2 = fb[256 + t], q3 = fb[512 + t], q4 = fb[768 + t];
    float part[10] = {q1 * q1, q2 * q2, q3 * q3, q4 * q4,
                      q1 * q2, q1 * q3, q1 * q4, q2 * q3, q2 * q4, q3 * q4};
    __shared__ float sr[10][4];
    int lane = t & 63, wid = t >> 6;
#pragma unroll
    for (int i = 0; i < 10; i++) {
        float r = part[i];
#pragma unroll
        for (int s = 32; s > 0; s >>= 1) r += __shfl_xor(r, s);
        if (lane == 0) sr[i][wid] = r;
    }
    __syncthreads();
    if (t == 0) {
        float tot[10];
#pragma unroll
        for (int i = 0; i < 10; i++) tot[i] = sr[i][0] + sr[i][1] + sr[i][2] + sr[i][3];
        float n_[5] = {0.f, tot[0], tot[1], tot[2], tot[3]};
        float dd[5][5];
        dd[1][1] = tot[0]; dd[2][2] = tot[1]; dd[3][3] = tot[2]; dd[4][4] = tot[3];
        dd[1][2] = dd[2][1] = tot[4]; dd[1][3] = dd[3][1] = tot[5];
        dd[1][4] = dd[4][1] = tot[6]; dd[2][3] = dd[3][2] = tot[7];
        dd[2][4] = dd[4][2] = tot[8]; dd[3][4] = dd[4][3] = tot[9];
        float Q = tot[0] + tot[1] + tot[2] + tot[3];   // ||feats||^2
        float d2[5][5];
        d2[0][0] = 0.f;
        for (int i = 1; i < 5; i++) {
            float v = Q + n_[i] - 2.f * dd[1][i];      // <X0,Xi> = <q1,qi>
            d2[0][i] = v; d2[i][0] = v;
        }
        for (int i = 1; i < 5; i++)
            for (int j = 1; j < 5; j++)
                d2[i][j] = (i == j) ? 0.f : (n_[i] + n_[j] - 2.f * dd[i][j]);
        // top-4 of (-d2) keeps lower indices on ties -> drop the LAST argmax of d2
        int drp[5];
        for (int r = 0; r < 5; r++) {
            int dm = 0; float vm = d2[r][0];
            for (int s = 1; s < 5; s++)
                if (d2[r][s] >= vm) { vm = d2[r][s]; dm = s; }
            drp[r] = dm;
            dropped[b * 5 + r] = dm;
        }
        // A_hat = A + I ; row degrees; An = A_hat * dinv_t * dinv_s ; cm = col mean
        float Ah[5][5], deg[5], dinv[5];
        for (int r = 0; r < 5; r++) {
            float dsum = 0.f;
            for (int s = 0; s < 5; s++) {
                float a = ((s != drp[r]) ? 1.f : 0.f) + ((s == r) ? 1.f : 0.f);
                Ah[r][s] = a; dsum += a;
            }
            deg[r] = dsum;
            dinv[r] = dsum > 0.f ? 1.f / sqrtf(dsum) : 0.f;
        }
        float colsum[5] = {0.f, 0.f, 0.f, 0.f, 0.f};
        for (int r = 0; r < 5; r++)
            for (int s = 0; s < 5; s++) {
                float v = Ah[r][s] * dinv[r] * dinv[s];
                An[b * 25 + r * 5 + s] = v;
                colsum[s] += v;
            }
        for (int s = 0; s < 5; s++) cm[b * 5 + s] = colsum[s] * 0.2f;
    }
}

// ---------------- agg = An @ Xg  (Xg built implicitly) ----------------
__global__ __launch_bounds__(256) void k_agg(const float* __restrict__ feats,
                                             const float* __restrict__ An,
                                             float* __restrict__ agg) {
    int b = blockIdx.x;
    __shared__ float sAn[25];
    if (threadIdx.x < 25) sAn[threadIdx.x] = An[b * 25 + threadIdx.x];
    __syncthreads();
    const float* fb = feats + (size_t)b * 1024;
    for (int f = threadIdx.x; f < 1024; f += 256) {
        float a0 = fb[f];
        bool inq = f < 256;
        float v1 = 0.f, v2 = 0.f, v3 = 0.f, v4 = 0.f;
        if (inq) { v1 = fb[f]; v2 = fb[256 + f]; v3 = fb[512 + f]; v4 = fb[768 + f]; }
#pragma unroll
        for (int t = 0; t < 5; t++) {
            float r = sAn[t * 5] * a0;
            if (inq)
                r += sAn[t * 5 + 1] * v1 + sAn[t * 5 + 2] * v2 +
                     sAn[t * 5 + 3] * v3 + sAn[t * 5 + 4] * v4;
            agg[((size_t)b * 5 + t) * 1024 + f] = r;
        }
    }
}

// ---------------- expert layer 1 + fold mean_t:  p[pair][h] = sum_s cm[s]*relu((agg@w1)[s][h]+b1)
__global__ __launch_bounds__(256) void k_h1p(const float* __restrict__ agg,
                                             const float* __restrict__ w1,
                                             const float* __restrict__ b1,
                                             const float* __restrict__ cm,
                                             const int* __restrict__ top_idx,
                                             float* __restrict__ p) {
    int pair = blockIdx.x;                    // 0..127 = b*2+k
    int h = blockIdx.y * 256 + threadIdx.x;   // 0..511
    int b = pair >> 1;
    int c = top_idx[pair];
    const f32x4* av = (const f32x4*)(agg + (size_t)b * 5 * 1024);
    const float* wc = w1 + (size_t)c * 1024 * 512;
    float acc[5] = {0.f, 0.f, 0.f, 0.f, 0.f};
#pragma unroll 2
    for (int f4 = 0; f4 < 256; f4++) {
        f32x4 a[5];
#pragma unroll
        for (int t = 0; t < 5; t++) a[t] = av[t * 256 + f4];   // uniform -> s_load_x4
        int f = f4 * 4;
#pragma unroll
        for (int j = 0; j < 4; j++) {
            float w = wc[(size_t)(f + j) * 512 + h];           // coalesced
#pragma unroll
            for (int t = 0; t < 5; t++) acc[t] = fmaf(a[t][j], w, acc[t]);
        }
    }
    float pv = 0.f;
#pragma unroll
    for (int t = 0; t < 5; t++) {
        float hv = fmaxf(acc[t] + b1[c * 512 + h], 0.f);
        pv = fmaf(cm[b * 5 + t], hv, pv);
    }
    p[pair * 512 + h] = pv;
}

// ---------------- expert layer 2: g[pair][o] = p @ w2[c] + b2[c] ----------------
__global__ __launch_bounds__(256) void k_g(const float* __restrict__ p,
                                           const float* __restrict__ w2,
                                           const float* __restrict__ b2,
                                           const int* __restrict__ top_idx,
                                           float* __restrict__ g) {
    int pair = blockIdx.x;
    int o = threadIdx.x;
    int c = top_idx[pair];
    const f32x4* pv = (const f32x4*)(p + (size_t)pair * 512);
    const float* wc = w2 + (size_t)c * 512 * 256;
    float acc = b2[c * 256 + o];
#pragma unroll 2
    for (int h4 = 0; h4 < 128; h4++) {
        f32x4 pr = pv[h4];                                     // uniform
        int hh = h4 * 4;
#pragma unroll
        for (int j = 0; j < 4; j++)
            acc = fmaf(pr[j], wc[(size_t)(hh + j) * 256 + o], acc);
    }
    g[pair * 256 + o] = acc;
}

// ---------------- M = comb @ fin_w  ([128,256]@[256,80]) ----------------
__global__ __launch_bounds__(128) void k_M(const float* __restrict__ g,
                                           const float* __restrict__ finw,
                                           float* __restrict__ M) {
    int n = blockIdx.x;
    int c = threadIdx.x;
    if (c >= 80) return;
    const f32x4* gv = (const f32x4*)(g + (size_t)n * 256);
    float acc = 0.f;
    for (int o4 = 0; o4 < 64; o4++) {
        f32x4 gr = gv[o4];                                     // uniform
#pragma unroll
        for (int j = 0; j < 4; j++)
            acc = fmaf(gr[j], finw[(o4 * 4 + j) * 80 + c], acc);
    }
    M[n * 80 + c] = acc;
}

// ---------------- final GCN (rows<5 mix with Af/5, rows>=5 identity) + mean over k ----------
__global__ __launch_bounds__(128) void k_out(const float* __restrict__ M,
                                             const float* __restrict__ finb,
                                             const int* __restrict__ dropped,
                                             float* __restrict__ out) {
    int b = blockIdx.x;
    int c = threadIdx.x;
    if (c >= 80) return;
    float bias = finb[c];
    float r = 0.f;
#pragma unroll
    for (int k = 0; k < 2; k++) {
        int n = b * 2 + k;
        float fin;
        if (n < 5) {
            float s = 0.f;
            for (int m = 0; m < 5; m++) {
                float a = ((m != dropped[63 * 5 + n]) ? 1.f : 0.f) + ((m == n) ? 1.f : 0.f);
                s += a * M[m * 80 + c];
            }
            fin = s * 0.2f + bias;   // dinv=1/sqrt(5) both sides -> /5
        } else {
            fin = M[n * 80 + c] + bias;
        }
        r += fin;
    }
    out[b * 80 + c] = r * 0.5f;
}

extern "C" void kernel_launch(void* const* d_in, const int* in_sizes, int n_in,
                              void* d_out, int out_size, void* d_ws, size_t ws_size,
                              hipStream_t stream) {
    const float* x       = (const float*)d_in[0];
    const float* conv1_w = (const float*)d_in[1];
    const float* conv1_b = (const float*)d_in[2];
    const float* conv2_w = (const float*)d_in[3];
    const float* conv2_b = (const float*)d_in[4];
    const float* fcf_w   = (const float*)d_in[5];
    const float* fcf_b   = (const float*)d_in[6];
    const float* fcc_w   = (const float*)d_in[7];
    const float* fcc_b   = (const float*)d_in[8];
    const float* gnn_w1  = (const float*)d_in[9];
    const float* gnn_b1  = (const float*)d_in[10];
    const float* gnn_w2  = (const float*)d_in[11];
    const float* gnn_b2  = (const float*)d_in[12];
    const float* fin_w   = (const float*)d_in[13];
    const float* fin_b   = (const float*)d_in[14];
    float* out = (float*)d_out;

    // bump allocator on d_ws (total ~105 MB)
    char* ws = (char*)d_ws;
    size_t off = 0;
    auto alloc = [&](size_t bytes) {
        void* pp = ws + off;
        off = (off + bytes + 255) & ~(size_t)255;
        return pp;
    };
    float* h1conv  = (float*)alloc((size_t)64 * 32 * 112 * 112 * 4);  // 102.8 MB
    float* wt1     = (float*)alloc(864 * 4);
    float* wt2     = (float*)alloc(18432 * 4);
    float* pooled  = (float*)alloc(4096 * 4);
    float* feats   = (float*)alloc(65536 * 4);
    int*   top_idx = (int*)alloc(128 * 4);
    float* An      = (float*)alloc(1600 * 4);
    float* cm      = (float*)alloc(320 * 4);
    int*   dropped = (int*)alloc(320 * 4);
    float* agg     = (float*)alloc(327680 * 4);
    float* p       = (float*)alloc(65536 * 4);
    float* g       = (float*)alloc(32768 * 4);
    float* Mm      = (float*)alloc(10240 * 4);
    (void)ws_size; (void)in_sizes; (void)n_in; (void)out_size;

    k_zero<<<16, 256, 0, stream>>>(pooled, 4096);
    k_prep<<<72, 256, 0, stream>>>(conv1_w, conv2_w, wt1, wt2);
    k_conv1<<<3136, 256, 0, stream>>>(x, wt1, conv1_b, h1conv);
    k_conv2gap<<<dim3(13, 64), 256, 0, stream>>>(h1conv, wt2, conv2_b, pooled);
    k_fcf<<<64, 256, 0, stream>>>(pooled, fcf_w, fcf_b, feats);
    k_fcc_top2<<<64, 128, 0, stream>>>(feats, fcc_w, fcc_b, top_idx);
    k_graph<<<64, 256, 0, stream>>>(feats, An, cm, dropped);
    k_agg<<<64, 256, 0, stream>>>(feats, An, agg);
    k_h1p<<<dim3(128, 2), 256, 0, stream>>>(agg, gnn_w1, gnn_b1, cm, top_idx, p);
    k_g<<<128, 256, 0, stream>>>(p, gnn_w2, gnn_b2, top_idx, g);
    k_M<<<128, 128, 0, stream>>>(g, fin_w, Mm);
    k_out<<<64, 128, 0, stream>>>(Mm, fin_b, dropped, out);
}